// Round 1
// baseline (60.868 us; speedup 1.0000x reference)
//
#include <hip/hip_runtime.h>

#define EDGE_EPS 1e-8f

struct V3 { float x, y, z; };
struct V4 { float x, y, z, w; };

__device__ __forceinline__ V3 v3(float a, float b, float c) { V3 r{a,b,c}; return r; }

__device__ __forceinline__ V3 addv(V3 a, V3 b) { return v3(a.x+b.x, a.y+b.y, a.z+b.z); }
__device__ __forceinline__ V3 subv(V3 a, V3 b) { return v3(a.x-b.x, a.y-b.y, a.z-b.z); }
__device__ __forceinline__ V3 muls(V3 a, float s) { return v3(a.x*s, a.y*s, a.z*s); }
__device__ __forceinline__ float dotv(V3 a, V3 b) { return a.x*b.x + a.y*b.y + a.z*b.z; }
__device__ __forceinline__ V3 crossv(V3 a, V3 b) {
    return v3(a.y*b.z - a.z*b.y,
              a.z*b.x - a.x*b.z,
              a.x*b.y - a.y*b.x);
}

// q1*q2: w = w1w2 - v1.v2 ; v = w1 v2 + w2 v1 + v1 x v2
__device__ __forceinline__ V4 qmul(V4 a, V4 b) {
    V3 v1 = v3(a.x, a.y, a.z), v2 = v3(b.x, b.y, b.z);
    V3 c = crossv(v1, v2);
    V4 r;
    r.x = a.w*b.x + b.w*a.x + c.x;
    r.y = a.w*b.y + b.w*a.y + c.y;
    r.z = a.w*b.z + b.w*a.z + c.z;
    r.w = a.w*b.w - dotv(v1, v2);
    return r;
}

// t + 2 * v x (v x t + w t)
__device__ __forceinline__ V3 qact(V4 q, V3 t) {
    V3 v = v3(q.x, q.y, q.z);
    V3 inner = crossv(v, t);
    inner.x += q.w * t.x; inner.y += q.w * t.y; inner.z += q.w * t.z;
    V3 o = crossv(v, inner);
    return v3(t.x + 2.0f*o.x, t.y + 2.0f*o.y, t.z + 2.0f*o.z);
}

__device__ __forceinline__ V3 qlog(V4 q) {
    float sgn = (q.w >= 0.0f) ? 1.0f : -1.0f;
    float x = q.x * sgn, y = q.y * sgn, z = q.z * sgn, w = q.w * sgn;
    float n = sqrtf(x*x + y*y + z*z);
    float theta = 2.0f * atan2f(n, w);
    float coef = (n < EDGE_EPS) ? 2.0f : theta / fmaxf(n, EDGE_EPS);
    return v3(coef*x, coef*y, coef*z);
}

__device__ __forceinline__ V4 qinvq(V4 q) { V4 r{-q.x,-q.y,-q.z,q.w}; return r; }

__global__ void __launch_bounds__(256)
swc_kernel(const float* __restrict__ R0, const float* __restrict__ t0,
           const float4* __restrict__ rot,  const float* __restrict__ trans,
           const float* __restrict__ vel,   const float* __restrict__ ba,
           const float* __restrict__ bg,    const float4* __restrict__ dRq,
           const float* __restrict__ dv,    const float* __restrict__ dp,
           const float* __restrict__ dt,    const float4* __restrict__ vRq,
           const float* __restrict__ vt,    float* __restrict__ out, int N)
{
    int k = blockIdx.x * blockDim.x + threadIdx.x;
    if (k >= N) return;

    // --- loads ---
    V4 Rk;
    V3 tk;
    if (k == 0) {
        Rk = V4{R0[0], R0[1], R0[2], R0[3]};
        tk = v3(t0[0], t0[1], t0[2]);
    } else {
        float4 r = rot[k-1];
        Rk = V4{r.x, r.y, r.z, r.w};
        tk = v3(trans[3*(k-1)+0], trans[3*(k-1)+1], trans[3*(k-1)+2]);
    }
    float4 r1 = rot[k];
    V4 Rk1{r1.x, r1.y, r1.z, r1.w};
    V3 tk1 = v3(trans[3*k+0], trans[3*k+1], trans[3*k+2]);

    V3 vk   = v3(vel[3*k+0],     vel[3*k+1],     vel[3*k+2]);
    V3 vk1  = v3(vel[3*(k+1)+0], vel[3*(k+1)+1], vel[3*(k+1)+2]);
    V3 bak  = v3(ba[3*k+0],      ba[3*k+1],      ba[3*k+2]);
    V3 bak1 = v3(ba[3*(k+1)+0],  ba[3*(k+1)+1],  ba[3*(k+1)+2]);
    V3 bgk  = v3(bg[3*k+0],      bg[3*k+1],      bg[3*k+2]);
    V3 bgk1 = v3(bg[3*(k+1)+0],  bg[3*(k+1)+1],  bg[3*(k+1)+2]);

    float dtk = dt[k];
    float4 dr = dRq[k];  V4 dRk{dr.x, dr.y, dr.z, dr.w};
    float4 vr = vRq[k];  V4 vRk{vr.x, vr.y, vr.z, vr.w};
    V3 dvk = v3(dv[3*k+0], dv[3*k+1], dv[3*k+2]);
    V3 dpk = v3(dp[3*k+0], dp[3*k+1], dp[3*k+2]);
    V3 vtk = v3(vt[3*k+0], vt[3*k+1], vt[3*k+2]);

    // --- math ---
    V4 Rinv = qinvq(Rk);
    V4 relR = qmul(Rinv, Rk1);
    V3 dtrans = subv(tk1, tk);
    V3 rel_t_est = qact(Rinv, dtrans);

    // r_rot = qlog(qinv(dR) * relR) + dt * bg_k
    V3 r_rot = addv(qlog(qmul(qinvq(dRk), relR)), muls(bgk, dtk));

    // r_cross = qact(Rinv, dtrans - v_k*dt) - dp + 0.5 dt^2 ba_k
    V3 r_cross = qact(Rinv, subv(dtrans, muls(vk, dtk)));
    r_cross = addv(subv(r_cross, dpk), muls(bak, 0.5f*dtk*dtk));

    // r_deltav = v_kp1 - v_k - qact(R_k, dv) + dt*ba_k
    V3 r_deltav = addv(subv(subv(vk1, vk), qact(Rk, dvk)), muls(bak, dtk));

    V3 r_vis_rot = qlog(qmul(qinvq(vRk), relR));
    V3 r_vis_t   = subv(rel_t_est, vtk);

    V3 r_ba  = subv(bak1, bak);
    V3 r_bg  = subv(bgk1, bgk);

    // --- stores: out[k, row, c] ---
    float* o = out + (size_t)k * 27;
    o[ 0] = r_vis_rot.x; o[ 1] = r_vis_rot.y; o[ 2] = r_vis_rot.z;
    o[ 3] = r_vis_t.x;   o[ 4] = r_vis_t.y;   o[ 5] = r_vis_t.z;
    o[ 6] = r_rot.x;     o[ 7] = r_rot.y;     o[ 8] = r_rot.z;
    o[ 9] = r_cross.x;   o[10] = r_cross.y;   o[11] = r_cross.z;
    o[12] = r_deltav.x;  o[13] = r_deltav.y;  o[14] = r_deltav.z;
    o[15] = r_ba.x;      o[16] = r_ba.y;      o[17] = r_ba.z;
    o[18] = r_bg.x;      o[19] = r_bg.y;      o[20] = r_bg.z;
    o[21] = bak.x;       o[22] = bak.y;       o[23] = bak.z;
    o[24] = bgk.x;       o[25] = bgk.y;       o[26] = bgk.z;
}

extern "C" void kernel_launch(void* const* d_in, const int* in_sizes, int n_in,
                              void* d_out, int out_size, void* d_ws, size_t ws_size,
                              hipStream_t stream) {
    const float*  R0    = (const float*)d_in[0];
    const float*  t0    = (const float*)d_in[1];
    const float4* rot   = (const float4*)d_in[2];
    const float*  trans = (const float*)d_in[3];
    const float*  vel   = (const float*)d_in[4];
    const float*  ba    = (const float*)d_in[5];
    const float*  bg    = (const float*)d_in[6];
    const float4* dRq   = (const float4*)d_in[7];
    const float*  dv    = (const float*)d_in[8];
    const float*  dp    = (const float*)d_in[9];
    const float*  dt    = (const float*)d_in[10];
    const float4* vRq   = (const float4*)d_in[11];
    const float*  vt    = (const float*)d_in[12];
    float* out = (float*)d_out;

    int N = in_sizes[2] / 4;   // rotations: (W-1, 4)
    int block = 256;
    int grid = (N + block - 1) / block;
    swc_kernel<<<grid, block, 0, stream>>>(R0, t0, rot, trans, vel, ba, bg,
                                           dRq, dv, dp, dt, vRq, vt, out, N);
}

// Round 2
// 60.333 us; speedup vs baseline: 1.0089x; 1.0089x over previous
//
#include <hip/hip_runtime.h>

#define EDGE_EPS 1e-8f

struct V3 { float x, y, z; };
struct V4 { float x, y, z, w; };

__device__ __forceinline__ V3 v3(float a, float b, float c) { V3 r{a,b,c}; return r; }

__device__ __forceinline__ V3 addv(V3 a, V3 b) { return v3(a.x+b.x, a.y+b.y, a.z+b.z); }
__device__ __forceinline__ V3 subv(V3 a, V3 b) { return v3(a.x-b.x, a.y-b.y, a.z-b.z); }
__device__ __forceinline__ V3 muls(V3 a, float s) { return v3(a.x*s, a.y*s, a.z*s); }
__device__ __forceinline__ float dotv(V3 a, V3 b) { return a.x*b.x + a.y*b.y + a.z*b.z; }
__device__ __forceinline__ V3 crossv(V3 a, V3 b) {
    return v3(a.y*b.z - a.z*b.y,
              a.z*b.x - a.x*b.z,
              a.x*b.y - a.y*b.x);
}

__device__ __forceinline__ V4 qmul(V4 a, V4 b) {
    V3 v1 = v3(a.x, a.y, a.z), v2 = v3(b.x, b.y, b.z);
    V3 c = crossv(v1, v2);
    V4 r;
    r.x = a.w*b.x + b.w*a.x + c.x;
    r.y = a.w*b.y + b.w*a.y + c.y;
    r.z = a.w*b.z + b.w*a.z + c.z;
    r.w = a.w*b.w - dotv(v1, v2);
    return r;
}

__device__ __forceinline__ V3 qact(V4 q, V3 t) {
    V3 v = v3(q.x, q.y, q.z);
    V3 inner = crossv(v, t);
    inner.x += q.w * t.x; inner.y += q.w * t.y; inner.z += q.w * t.z;
    V3 o = crossv(v, inner);
    return v3(t.x + 2.0f*o.x, t.y + 2.0f*o.y, t.z + 2.0f*o.z);
}

__device__ __forceinline__ V3 qlog(V4 q) {
    float sgn = (q.w >= 0.0f) ? 1.0f : -1.0f;
    float x = q.x * sgn, y = q.y * sgn, z = q.z * sgn, w = q.w * sgn;
    float n = sqrtf(x*x + y*y + z*z);
    float theta = 2.0f * atan2f(n, w);
    float coef = (n < EDGE_EPS) ? 2.0f : theta / fmaxf(n, EDGE_EPS);
    return v3(coef*x, coef*y, coef*z);
}

__device__ __forceinline__ V4 qinvq(V4 q) { V4 r{-q.x,-q.y,-q.z,q.w}; return r; }

__global__ void __launch_bounds__(256)
swc_kernel(const float* __restrict__ R0, const float* __restrict__ t0,
           const float4* __restrict__ rot,  const float* __restrict__ trans,
           const float* __restrict__ vel,   const float* __restrict__ ba,
           const float* __restrict__ bg,    const float4* __restrict__ dRq,
           const float* __restrict__ dv,    const float* __restrict__ dp,
           const float* __restrict__ dt,    const float4* __restrict__ vRq,
           const float* __restrict__ vt,    float* __restrict__ out, int N)
{
    // smem carve (floats):
    //  input phase : trans[771] vel[771] ba[771] bg[771] dv[768] dp[768] vt[768] = 5388
    //  output phase: 256*27 = 6912 (reuses the whole buffer)
    __shared__ __align__(16) float smem[6912];
    float* s_trans = smem + 0;
    float* s_vel   = smem + 771;
    float* s_ba    = smem + 1542;
    float* s_bg    = smem + 2313;
    float* s_dv    = smem + 3084;
    float* s_dp    = smem + 3852;
    float* s_vt    = smem + 4620;

    const int base = blockIdx.x * 256;
    const int tid  = threadIdx.x;
    const int k    = base + tid;
    const bool active = (k < N);

    const int NT = N * 3;          // floats in trans/dv/dp/vt
    const int WT = (N + 1) * 3;    // floats in vel/ba/bg

    // ---- stage inputs (coalesced stride-1 dword loads) ----
    // trans entries [base-1 .. base+255]  (entry -1 comes from t0)
    #pragma unroll
    for (int rep = 0; rep < 4; ++rep) {
        int j = tid + rep * 256;
        if (j < 771) {
            int gi = (base - 1) * 3 + j;
            float v;
            if (gi < 0)        v = t0[gi + 3];
            else if (gi < NT)  v = trans[gi];
            else               v = 0.0f;
            s_trans[j] = v;
        }
    }
    // vel/ba/bg entries [base .. base+256]
    #pragma unroll
    for (int rep = 0; rep < 4; ++rep) {
        int j = tid + rep * 256;
        if (j < 771) {
            int gi = base * 3 + j;
            bool ok = gi < WT;
            s_vel[j] = ok ? vel[gi] : 0.0f;
            s_ba [j] = ok ? ba [gi] : 0.0f;
            s_bg [j] = ok ? bg [gi] : 0.0f;
        }
    }
    // dv/dp/vt entries [base .. base+255]
    #pragma unroll
    for (int rep = 0; rep < 3; ++rep) {
        int j = tid + rep * 256;
        int gi = base * 3 + j;
        bool ok = gi < NT;
        s_dv[j] = ok ? dv[gi] : 0.0f;
        s_dp[j] = ok ? dp[gi] : 0.0f;
        s_vt[j] = ok ? vt[gi] : 0.0f;
    }
    __syncthreads();

    // ---- compute (results kept in registers) ----
    float res[27];
    if (active) {
        const int i3 = tid * 3;
        V3 tk   = v3(s_trans[i3],   s_trans[i3+1], s_trans[i3+2]);
        V3 tk1  = v3(s_trans[i3+3], s_trans[i3+4], s_trans[i3+5]);
        V3 vk   = v3(s_vel[i3],     s_vel[i3+1],   s_vel[i3+2]);
        V3 vk1  = v3(s_vel[i3+3],   s_vel[i3+4],   s_vel[i3+5]);
        V3 bak  = v3(s_ba[i3],      s_ba[i3+1],    s_ba[i3+2]);
        V3 bak1 = v3(s_ba[i3+3],    s_ba[i3+4],    s_ba[i3+5]);
        V3 bgk  = v3(s_bg[i3],      s_bg[i3+1],    s_bg[i3+2]);
        V3 bgk1 = v3(s_bg[i3+3],    s_bg[i3+4],    s_bg[i3+5]);
        V3 dvk  = v3(s_dv[i3],      s_dv[i3+1],    s_dv[i3+2]);
        V3 dpk  = v3(s_dp[i3],      s_dp[i3+1],    s_dp[i3+2]);
        V3 vtk  = v3(s_vt[i3],      s_vt[i3+1],    s_vt[i3+2]);

        V4 Rk;
        if (k == 0) {
            Rk = V4{R0[0], R0[1], R0[2], R0[3]};
        } else {
            float4 r = rot[k-1];
            Rk = V4{r.x, r.y, r.z, r.w};
        }
        float4 r1 = rot[k];
        V4 Rk1{r1.x, r1.y, r1.z, r1.w};
        float4 dr = dRq[k];  V4 dRk{dr.x, dr.y, dr.z, dr.w};
        float4 vr = vRq[k];  V4 vRk{vr.x, vr.y, vr.z, vr.w};
        float dtk = dt[k];

        V4 Rinv = qinvq(Rk);
        V4 relR = qmul(Rinv, Rk1);
        V3 dtrans = subv(tk1, tk);
        V3 rel_t_est = qact(Rinv, dtrans);

        V3 r_rot = addv(qlog(qmul(qinvq(dRk), relR)), muls(bgk, dtk));

        V3 r_cross = qact(Rinv, subv(dtrans, muls(vk, dtk)));
        r_cross = addv(subv(r_cross, dpk), muls(bak, 0.5f*dtk*dtk));

        V3 r_deltav = addv(subv(subv(vk1, vk), qact(Rk, dvk)), muls(bak, dtk));

        V3 r_vis_rot = qlog(qmul(qinvq(vRk), relR));
        V3 r_vis_t   = subv(rel_t_est, vtk);

        res[ 0] = r_vis_rot.x; res[ 1] = r_vis_rot.y; res[ 2] = r_vis_rot.z;
        res[ 3] = r_vis_t.x;   res[ 4] = r_vis_t.y;   res[ 5] = r_vis_t.z;
        res[ 6] = r_rot.x;     res[ 7] = r_rot.y;     res[ 8] = r_rot.z;
        res[ 9] = r_cross.x;   res[10] = r_cross.y;   res[11] = r_cross.z;
        res[12] = r_deltav.x;  res[13] = r_deltav.y;  res[14] = r_deltav.z;
        res[15] = bak1.x - bak.x; res[16] = bak1.y - bak.y; res[17] = bak1.z - bak.z;
        res[18] = bgk1.x - bgk.x; res[19] = bgk1.y - bgk.y; res[20] = bgk1.z - bgk.z;
        res[21] = bak.x;       res[22] = bak.y;       res[23] = bak.z;
        res[24] = bgk.x;       res[25] = bgk.y;       res[26] = bgk.z;
    }
    __syncthreads();   // done reading input LDS; reuse buffer for outputs

    if (active) {
        #pragma unroll
        for (int r = 0; r < 27; ++r) smem[tid * 27 + r] = res[r];
    }
    __syncthreads();

    // ---- coalesced block store ----
    const int cnt = min(256, N - base);      // active edges in this block
    float* og = out + (size_t)base * 27;
    if (cnt == 256) {
        const float4* s4 = reinterpret_cast<const float4*>(smem);
        float4* o4 = reinterpret_cast<float4*>(og);
        #pragma unroll
        for (int rep = 0; rep < 7; ++rep) {
            int j = tid + rep * 256;
            if (j < 1728) o4[j] = s4[j];
        }
    } else {
        int nfl = cnt * 27;
        for (int j = tid; j < nfl; j += 256) og[j] = smem[j];
    }
}

extern "C" void kernel_launch(void* const* d_in, const int* in_sizes, int n_in,
                              void* d_out, int out_size, void* d_ws, size_t ws_size,
                              hipStream_t stream) {
    const float*  R0    = (const float*)d_in[0];
    const float*  t0    = (const float*)d_in[1];
    const float4* rot   = (const float4*)d_in[2];
    const float*  trans = (const float*)d_in[3];
    const float*  vel   = (const float*)d_in[4];
    const float*  ba    = (const float*)d_in[5];
    const float*  bg    = (const float*)d_in[6];
    const float4* dRq   = (const float4*)d_in[7];
    const float*  dv    = (const float*)d_in[8];
    const float*  dp    = (const float*)d_in[9];
    const float*  dt    = (const float*)d_in[10];
    const float4* vRq   = (const float4*)d_in[11];
    const float*  vt    = (const float*)d_in[12];
    float* out = (float*)d_out;

    int N = in_sizes[2] / 4;   // rotations: (W-1, 4)
    int block = 256;
    int grid = (N + block - 1) / block;
    swc_kernel<<<grid, block, 0, stream>>>(R0, t0, rot, trans, vel, ba, bg,
                                           dRq, dv, dp, dt, vRq, vt, out, N);
}

// Round 4
// 44.979 us; speedup vs baseline: 1.3533x; 1.3414x over previous
//
#include <hip/hip_runtime.h>

#define EDGE_EPS 1e-8f

typedef float fvec4 __attribute__((ext_vector_type(4)));

struct V3 { float x, y, z; };
struct V4 { float x, y, z, w; };

__device__ __forceinline__ V3 v3(float a, float b, float c) { V3 r{a,b,c}; return r; }

__device__ __forceinline__ V3 addv(V3 a, V3 b) { return v3(a.x+b.x, a.y+b.y, a.z+b.z); }
__device__ __forceinline__ V3 subv(V3 a, V3 b) { return v3(a.x-b.x, a.y-b.y, a.z-b.z); }
__device__ __forceinline__ V3 muls(V3 a, float s) { return v3(a.x*s, a.y*s, a.z*s); }
__device__ __forceinline__ float dotv(V3 a, V3 b) { return a.x*b.x + a.y*b.y + a.z*b.z; }
__device__ __forceinline__ V3 crossv(V3 a, V3 b) {
    return v3(a.y*b.z - a.z*b.y,
              a.z*b.x - a.x*b.z,
              a.x*b.y - a.y*b.x);
}

__device__ __forceinline__ V4 qmul(V4 a, V4 b) {
    V3 v1 = v3(a.x, a.y, a.z), v2 = v3(b.x, b.y, b.z);
    V3 c = crossv(v1, v2);
    V4 r;
    r.x = a.w*b.x + b.w*a.x + c.x;
    r.y = a.w*b.y + b.w*a.y + c.y;
    r.z = a.w*b.z + b.w*a.z + c.z;
    r.w = a.w*b.w - dotv(v1, v2);
    return r;
}

__device__ __forceinline__ V3 qact(V4 q, V3 t) {
    V3 v = v3(q.x, q.y, q.z);
    V3 inner = crossv(v, t);
    inner.x += q.w * t.x; inner.y += q.w * t.y; inner.z += q.w * t.z;
    V3 o = crossv(v, inner);
    return v3(t.x + 2.0f*o.x, t.y + 2.0f*o.y, t.z + 2.0f*o.z);
}

__device__ __forceinline__ V3 qlog(V4 q) {
    float sgn = (q.w >= 0.0f) ? 1.0f : -1.0f;
    float x = q.x * sgn, y = q.y * sgn, z = q.z * sgn, w = q.w * sgn;
    float n = sqrtf(x*x + y*y + z*z);
    float theta = 2.0f * atan2f(n, w);
    float coef = (n < EDGE_EPS) ? 2.0f : theta / fmaxf(n, EDGE_EPS);
    return v3(coef*x, coef*y, coef*z);
}

__device__ __forceinline__ V4 qinvq(V4 q) { V4 r{-q.x,-q.y,-q.z,q.w}; return r; }

__global__ void __launch_bounds__(256)
swc_kernel(const float* __restrict__ R0, const float* __restrict__ t0,
           const float4* __restrict__ rot,  const float* __restrict__ trans,
           const float* __restrict__ vel,   const float* __restrict__ ba,
           const float* __restrict__ bg,    const float4* __restrict__ dRq,
           const float* __restrict__ dv,    const float* __restrict__ dp,
           const float* __restrict__ dt,    const float4* __restrict__ vRq,
           const float* __restrict__ vt,    float* __restrict__ out, int N)
{
    // smem carve (floats):
    //  input phase : trans[771] vel[771] ba[771] bg[771] dv[768] dp[768] vt[768] = 5388
    //  output phase: 256*27 = 6912 (reuses the whole buffer)
    __shared__ __align__(16) float smem[6912];
    float* s_trans = smem + 0;
    float* s_vel   = smem + 771;
    float* s_ba    = smem + 1542;
    float* s_bg    = smem + 2313;
    float* s_dv    = smem + 3084;
    float* s_dp    = smem + 3852;
    float* s_vt    = smem + 4620;

    const int base = blockIdx.x * 256;
    const int tid  = threadIdx.x;
    const int k    = base + tid;
    const bool active = (k < N);

    const int NT = N * 3;          // floats in trans/dv/dp/vt
    const int WT = (N + 1) * 3;    // floats in vel/ba/bg

    // ---- stage inputs (coalesced stride-1 dword loads) ----
    // trans entries [base-1 .. base+255]  (entry -1 comes from t0)
    #pragma unroll
    for (int rep = 0; rep < 4; ++rep) {
        int j = tid + rep * 256;
        if (j < 771) {
            int gi = (base - 1) * 3 + j;
            float v;
            if (gi < 0)        v = t0[gi + 3];
            else if (gi < NT)  v = trans[gi];
            else               v = 0.0f;
            s_trans[j] = v;
        }
    }
    // vel/ba/bg entries [base .. base+256]
    #pragma unroll
    for (int rep = 0; rep < 4; ++rep) {
        int j = tid + rep * 256;
        if (j < 771) {
            int gi = base * 3 + j;
            bool ok = gi < WT;
            s_vel[j] = ok ? vel[gi] : 0.0f;
            s_ba [j] = ok ? ba [gi] : 0.0f;
            s_bg [j] = ok ? bg [gi] : 0.0f;
        }
    }
    // dv/dp/vt entries [base .. base+255]
    #pragma unroll
    for (int rep = 0; rep < 3; ++rep) {
        int j = tid + rep * 256;
        int gi = base * 3 + j;
        bool ok = gi < NT;
        s_dv[j] = ok ? dv[gi] : 0.0f;
        s_dp[j] = ok ? dp[gi] : 0.0f;
        s_vt[j] = ok ? vt[gi] : 0.0f;
    }
    __syncthreads();

    // ---- compute (results kept in registers) ----
    float res[27];
    if (active) {
        const int i3 = tid * 3;
        V3 tk   = v3(s_trans[i3],   s_trans[i3+1], s_trans[i3+2]);
        V3 tk1  = v3(s_trans[i3+3], s_trans[i3+4], s_trans[i3+5]);
        V3 vk   = v3(s_vel[i3],     s_vel[i3+1],   s_vel[i3+2]);
        V3 vk1  = v3(s_vel[i3+3],   s_vel[i3+4],   s_vel[i3+5]);
        V3 bak  = v3(s_ba[i3],      s_ba[i3+1],    s_ba[i3+2]);
        V3 bak1 = v3(s_ba[i3+3],    s_ba[i3+4],    s_ba[i3+5]);
        V3 bgk  = v3(s_bg[i3],      s_bg[i3+1],    s_bg[i3+2]);
        V3 bgk1 = v3(s_bg[i3+3],    s_bg[i3+4],    s_bg[i3+5]);
        V3 dvk  = v3(s_dv[i3],      s_dv[i3+1],    s_dv[i3+2]);
        V3 dpk  = v3(s_dp[i3],      s_dp[i3+1],    s_dp[i3+2]);
        V3 vtk  = v3(s_vt[i3],      s_vt[i3+1],    s_vt[i3+2]);

        V4 Rk;
        if (k == 0) {
            Rk = V4{R0[0], R0[1], R0[2], R0[3]};
        } else {
            float4 r = rot[k-1];
            Rk = V4{r.x, r.y, r.z, r.w};
        }
        float4 r1 = rot[k];
        V4 Rk1{r1.x, r1.y, r1.z, r1.w};
        float4 dr = dRq[k];  V4 dRk{dr.x, dr.y, dr.z, dr.w};
        float4 vr = vRq[k];  V4 vRk{vr.x, vr.y, vr.z, vr.w};
        float dtk = dt[k];

        V4 Rinv = qinvq(Rk);
        V4 relR = qmul(Rinv, Rk1);
        V3 dtrans = subv(tk1, tk);
        V3 rel_t_est = qact(Rinv, dtrans);

        V3 r_rot = addv(qlog(qmul(qinvq(dRk), relR)), muls(bgk, dtk));

        V3 r_cross = qact(Rinv, subv(dtrans, muls(vk, dtk)));
        r_cross = addv(subv(r_cross, dpk), muls(bak, 0.5f*dtk*dtk));

        V3 r_deltav = addv(subv(subv(vk1, vk), qact(Rk, dvk)), muls(bak, dtk));

        V3 r_vis_rot = qlog(qmul(qinvq(vRk), relR));
        V3 r_vis_t   = subv(rel_t_est, vtk);

        res[ 0] = r_vis_rot.x; res[ 1] = r_vis_rot.y; res[ 2] = r_vis_rot.z;
        res[ 3] = r_vis_t.x;   res[ 4] = r_vis_t.y;   res[ 5] = r_vis_t.z;
        res[ 6] = r_rot.x;     res[ 7] = r_rot.y;     res[ 8] = r_rot.z;
        res[ 9] = r_cross.x;   res[10] = r_cross.y;   res[11] = r_cross.z;
        res[12] = r_deltav.x;  res[13] = r_deltav.y;  res[14] = r_deltav.z;
        res[15] = bak1.x - bak.x; res[16] = bak1.y - bak.y; res[17] = bak1.z - bak.z;
        res[18] = bgk1.x - bgk.x; res[19] = bgk1.y - bgk.y; res[20] = bgk1.z - bgk.z;
        res[21] = bak.x;       res[22] = bak.y;       res[23] = bak.z;
        res[24] = bgk.x;       res[25] = bgk.y;       res[26] = bgk.z;
    }
    __syncthreads();   // done reading input LDS; reuse buffer for outputs

    if (active) {
        #pragma unroll
        for (int r = 0; r < 27; ++r) smem[tid * 27 + r] = res[r];
    }
    __syncthreads();

    // ---- coalesced block store (non-temporal: keep L3 for inputs) ----
    const int cnt = min(256, N - base);      // active edges in this block
    float* og = out + (size_t)base * 27;
    if (cnt == 256) {
        const fvec4* s4 = reinterpret_cast<const fvec4*>(smem);
        fvec4* o4 = reinterpret_cast<fvec4*>(og);
        #pragma unroll
        for (int rep = 0; rep < 7; ++rep) {
            int j = tid + rep * 256;
            if (j < 1728) __builtin_nontemporal_store(s4[j], &o4[j]);
        }
    } else {
        int nfl = cnt * 27;
        for (int j = tid; j < nfl; j += 256) __builtin_nontemporal_store(smem[j], &og[j]);
    }
}

extern "C" void kernel_launch(void* const* d_in, const int* in_sizes, int n_in,
                              void* d_out, int out_size, void* d_ws, size_t ws_size,
                              hipStream_t stream) {
    const float*  R0    = (const float*)d_in[0];
    const float*  t0    = (const float*)d_in[1];
    const float4* rot   = (const float4*)d_in[2];
    const float*  trans = (const float*)d_in[3];
    const float*  vel   = (const float*)d_in[4];
    const float*  ba    = (const float*)d_in[5];
    const float*  bg    = (const float*)d_in[6];
    const float4* dRq   = (const float4*)d_in[7];
    const float*  dv    = (const float*)d_in[8];
    const float*  dp    = (const float*)d_in[9];
    const float*  dt    = (const float*)d_in[10];
    const float4* vRq   = (const float4*)d_in[11];
    const float*  vt    = (const float*)d_in[12];
    float* out = (float*)d_out;

    int N = in_sizes[2] / 4;   // rotations: (W-1, 4)
    int block = 256;
    int grid = (N + block - 1) / block;
    swc_kernel<<<grid, block, 0, stream>>>(R0, t0, rot, trans, vel, ba, bg,
                                           dRq, dv, dp, dt, vRq, vt, out, N);
}

// Round 5
// 42.912 us; speedup vs baseline: 1.4184x; 1.0482x over previous
//
#include <hip/hip_runtime.h>

#define EDGE_EPS 1e-8f

typedef float fvec4 __attribute__((ext_vector_type(4)));

struct V3 { float x, y, z; };
struct V4 { float x, y, z, w; };

__device__ __forceinline__ V3 v3(float a, float b, float c) { V3 r{a,b,c}; return r; }

__device__ __forceinline__ V3 addv(V3 a, V3 b) { return v3(a.x+b.x, a.y+b.y, a.z+b.z); }
__device__ __forceinline__ V3 subv(V3 a, V3 b) { return v3(a.x-b.x, a.y-b.y, a.z-b.z); }
__device__ __forceinline__ V3 muls(V3 a, float s) { return v3(a.x*s, a.y*s, a.z*s); }
__device__ __forceinline__ float dotv(V3 a, V3 b) { return a.x*b.x + a.y*b.y + a.z*b.z; }
__device__ __forceinline__ V3 crossv(V3 a, V3 b) {
    return v3(a.y*b.z - a.z*b.y,
              a.z*b.x - a.x*b.z,
              a.x*b.y - a.y*b.x);
}

__device__ __forceinline__ V4 qmul(V4 a, V4 b) {
    V3 v1 = v3(a.x, a.y, a.z), v2 = v3(b.x, b.y, b.z);
    V3 c = crossv(v1, v2);
    V4 r;
    r.x = a.w*b.x + b.w*a.x + c.x;
    r.y = a.w*b.y + b.w*a.y + c.y;
    r.z = a.w*b.z + b.w*a.z + c.z;
    r.w = a.w*b.w - dotv(v1, v2);
    return r;
}

__device__ __forceinline__ V3 qact(V4 q, V3 t) {
    V3 v = v3(q.x, q.y, q.z);
    V3 inner = crossv(v, t);
    inner.x += q.w * t.x; inner.y += q.w * t.y; inner.z += q.w * t.z;
    V3 o = crossv(v, inner);
    return v3(t.x + 2.0f*o.x, t.y + 2.0f*o.y, t.z + 2.0f*o.z);
}

__device__ __forceinline__ V3 qlog(V4 q) {
    float sgn = (q.w >= 0.0f) ? 1.0f : -1.0f;
    float x = q.x * sgn, y = q.y * sgn, z = q.z * sgn, w = q.w * sgn;
    float n = sqrtf(x*x + y*y + z*z);
    float theta = 2.0f * atan2f(n, w);
    float coef = (n < EDGE_EPS) ? 2.0f : theta / fmaxf(n, EDGE_EPS);
    return v3(coef*x, coef*y, coef*z);
}

__device__ __forceinline__ V4 qinvq(V4 q) { V4 r{-q.x,-q.y,-q.z,q.w}; return r; }

__device__ __forceinline__ V3 ld3(const float* __restrict__ p, int idx) {
    return v3(p[3*idx+0], p[3*idx+1], p[3*idx+2]);
}

__global__ void __launch_bounds__(128)
swc_kernel(const float* __restrict__ R0, const float* __restrict__ t0,
           const float4* __restrict__ rot,  const float* __restrict__ trans,
           const float* __restrict__ vel,   const float* __restrict__ ba,
           const float* __restrict__ bg,    const float4* __restrict__ dRq,
           const float* __restrict__ dv,    const float* __restrict__ dp,
           const float* __restrict__ dt,    const float4* __restrict__ vRq,
           const float* __restrict__ vt,    float* __restrict__ out, int N)
{
    // LDS: output transpose buffer only. 128*27 floats = 13824 B -> ~11 WG/CU.
    __shared__ __align__(16) float obuf[128 * 27];

    const int base = blockIdx.x * 128;
    const int tid  = threadIdx.x;
    const int k    = base + tid;
    const bool active = (k < N);

    float res[27];
    if (active) {
        // ---- direct loads ----
        V4 Rk; V3 tk;
        if (k == 0) {
            Rk = V4{R0[0], R0[1], R0[2], R0[3]};
            tk = v3(t0[0], t0[1], t0[2]);
        } else {
            float4 r = rot[k-1];
            Rk = V4{r.x, r.y, r.z, r.w};
            tk = ld3(trans, k-1);
        }
        float4 r1 = rot[k];
        V4 Rk1{r1.x, r1.y, r1.z, r1.w};
        float4 dr = dRq[k];  V4 dRk{dr.x, dr.y, dr.z, dr.w};
        float4 vr = vRq[k];  V4 vRk{vr.x, vr.y, vr.z, vr.w};
        float dtk = dt[k];

        V3 tk1  = ld3(trans, k);
        V3 vk   = ld3(vel, k);
        V3 vk1  = ld3(vel, k+1);    // vel has N+1 entries
        V3 bak  = ld3(ba, k);
        V3 bak1 = ld3(ba, k+1);
        V3 bgk  = ld3(bg, k);
        V3 bgk1 = ld3(bg, k+1);
        V3 dvk  = ld3(dv, k);
        V3 dpk  = ld3(dp, k);
        V3 vtk  = ld3(vt, k);

        // ---- math ----
        V4 Rinv = qinvq(Rk);
        V4 relR = qmul(Rinv, Rk1);
        V3 dtrans = subv(tk1, tk);
        V3 rel_t_est = qact(Rinv, dtrans);

        V3 r_rot = addv(qlog(qmul(qinvq(dRk), relR)), muls(bgk, dtk));

        V3 r_cross = qact(Rinv, subv(dtrans, muls(vk, dtk)));
        r_cross = addv(subv(r_cross, dpk), muls(bak, 0.5f*dtk*dtk));

        V3 r_deltav = addv(subv(subv(vk1, vk), qact(Rk, dvk)), muls(bak, dtk));

        V3 r_vis_rot = qlog(qmul(qinvq(vRk), relR));
        V3 r_vis_t   = subv(rel_t_est, vtk);

        res[ 0] = r_vis_rot.x; res[ 1] = r_vis_rot.y; res[ 2] = r_vis_rot.z;
        res[ 3] = r_vis_t.x;   res[ 4] = r_vis_t.y;   res[ 5] = r_vis_t.z;
        res[ 6] = r_rot.x;     res[ 7] = r_rot.y;     res[ 8] = r_rot.z;
        res[ 9] = r_cross.x;   res[10] = r_cross.y;   res[11] = r_cross.z;
        res[12] = r_deltav.x;  res[13] = r_deltav.y;  res[14] = r_deltav.z;
        res[15] = bak1.x - bak.x; res[16] = bak1.y - bak.y; res[17] = bak1.z - bak.z;
        res[18] = bgk1.x - bgk.x; res[19] = bgk1.y - bgk.y; res[20] = bgk1.z - bgk.z;
        res[21] = bak.x;       res[22] = bak.y;       res[23] = bak.z;
        res[24] = bgk.x;       res[25] = bgk.y;       res[26] = bgk.z;
    }

    if (active) {
        #pragma unroll
        for (int r = 0; r < 27; ++r) obuf[tid * 27 + r] = res[r];
    }
    __syncthreads();

    // ---- coalesced non-temporal block store ----
    const int cnt = min(128, N - base);
    float* og = out + (size_t)base * 27;
    if (cnt == 128) {
        const fvec4* s4 = reinterpret_cast<const fvec4*>(obuf);
        fvec4* o4 = reinterpret_cast<fvec4*>(og);
        #pragma unroll
        for (int rep = 0; rep < 7; ++rep) {
            int j = tid + rep * 128;
            if (j < 864) __builtin_nontemporal_store(s4[j], &o4[j]);
        }
    } else {
        int nfl = cnt * 27;
        for (int j = tid; j < nfl; j += 128) __builtin_nontemporal_store(obuf[j], &og[j]);
    }
}

extern "C" void kernel_launch(void* const* d_in, const int* in_sizes, int n_in,
                              void* d_out, int out_size, void* d_ws, size_t ws_size,
                              hipStream_t stream) {
    const float*  R0    = (const float*)d_in[0];
    const float*  t0    = (const float*)d_in[1];
    const float4* rot   = (const float4*)d_in[2];
    const float*  trans = (const float*)d_in[3];
    const float*  vel   = (const float*)d_in[4];
    const float*  ba    = (const float*)d_in[5];
    const float*  bg    = (const float*)d_in[6];
    const float4* dRq   = (const float4*)d_in[7];
    const float*  dv    = (const float*)d_in[8];
    const float*  dp    = (const float*)d_in[9];
    const float*  dt    = (const float*)d_in[10];
    const float4* vRq   = (const float4*)d_in[11];
    const float*  vt    = (const float*)d_in[12];
    float* out = (float*)d_out;

    int N = in_sizes[2] / 4;   // rotations: (W-1, 4)
    int block = 128;
    int grid = (N + block - 1) / block;
    swc_kernel<<<grid, block, 0, stream>>>(R0, t0, rot, trans, vel, ba, bg,
                                           dRq, dv, dp, dt, vRq, vt, out, N);
}